// Round 6
// baseline (790.638 us; speedup 1.0000x reference)
//
#include <hip/hip_runtime.h>

// Problem constants
#define S_LEN 2048
#define DM    2048
#define HQ_N  16
#define HKV_N 8
#define HD    128

typedef unsigned short u16;
typedef unsigned int   u32;
typedef short bf16x8 __attribute__((ext_vector_type(8)));
typedef float f32x4  __attribute__((ext_vector_type(4)));
typedef u16   u16x8  __attribute__((ext_vector_type(8)));

__device__ __forceinline__ float b2f(u16 u) {
  u32 x = ((u32)u) << 16;
  return __builtin_bit_cast(float, x);
}
__device__ __forceinline__ u16 f2b(float f) {  // RNE
  u32 u = __builtin_bit_cast(u32, f);
  u32 r = u + 0x7fffu + ((u >> 16) & 1u);
  return (u16)(r >> 16);
}

// direct global->LDS DMA, 16B per lane (dest must be waveuniform + lane*16)
#define GLOAD_LDS16(g, l)                                                     \
  __builtin_amdgcn_global_load_lds(                                           \
      (const __attribute__((address_space(1))) void*)(g),                     \
      (__attribute__((address_space(3))) void*)(l), 16, 0, 0)

// ---------------- f32 -> bf16 bulk convert (8 elems/thread) ---------------
__global__ void cvt_bf16(const float* __restrict__ src, u16* __restrict__ dst) {
  int id = blockIdx.x * blockDim.x + threadIdx.x;
  float4 a = ((const float4*)src)[id * 2];
  float4 b = ((const float4*)src)[id * 2 + 1];
  u16x8 o;
  o[0] = f2b(a.x); o[1] = f2b(a.y); o[2] = f2b(a.z); o[3] = f2b(a.w);
  o[4] = f2b(b.x); o[5] = f2b(b.y); o[6] = f2b(b.z); o[7] = f2b(b.w);
  ((u16x8*)dst)[id] = o;
}

// ---------------- RoPE tables: cos/sin[t][i], t<2048, i<64 ----------------
__global__ void rope_tables(float* __restrict__ cosT, float* __restrict__ sinT) {
  int id = blockIdx.x * blockDim.x + threadIdx.x;  // 131072
  int t = id >> 6, i = id & 63;
  float inv = (float)pow(10000.0, -(double)(2 * i) / 128.0);
  float ang = (float)t * inv;
  cosT[id] = cosf(ang);
  sinT[id] = sinf(ang);
}

// ---------------- GEMM: C(MxN) = A(MxK) * W(NxK)^T, bf16 in, f32 acc ------
// Staging via global_load_lds width=16 (m97 pattern).
// EPI 1: V-transpose -> Vt[(b*HKV+hk)*HD+d][s] bf16
// EPI 2: head-transpose -> dst[((b*HH+h)*S+s)*HD+d] bf16
// EPI 3: natural f32 (final output)
template <int EPI, int HH>
__global__ __launch_bounds__(256) void gemm_bt(const u16* __restrict__ A,
                                               const u16* __restrict__ W,
                                               void* __restrict__ Cv,
                                               int M, int N, int K) {
  __shared__ alignas(16) u16 As[128 * 32];
  __shared__ alignas(16) u16 Bs[128 * 32];
  const int tid  = threadIdx.x;
  const int lane = tid & 63;
  const int wave = tid >> 6;
  const int wr = (wave >> 1) * 64;  // wave row offset in tile
  const int wc = (wave & 1) * 64;   // wave col offset in tile
  const int bm = blockIdx.y * 128;
  const int bn = blockIdx.x * 128;
  const int r0 = tid >> 2;          // staging row 0..63
  const int c0 = (tid & 3) * 8;     // staging col {0,8,16,24}
  // LDS byte dest for staging = base + tid*16 (== (r0*32+c0)*2)
  u16* AsD = &As[tid * 8];
  u16* BsD = &Bs[tid * 8];
  const u16* Ap = A + (size_t)(bm + r0) * K + c0;
  const u16* Wp = W + (size_t)(bn + r0) * K + c0;
  const int cl = lane & 15;
  const int g8 = (lane >> 4) * 8;
  f32x4 acc[4][4] = {};
  for (int k0 = 0; k0 < K; k0 += 32) {
    __syncthreads();  // previous iteration's readers done
    GLOAD_LDS16(Ap + k0, AsD);
    GLOAD_LDS16(Ap + (size_t)64 * K + k0, AsD + 2048);
    GLOAD_LDS16(Wp + k0, BsD);
    GLOAD_LDS16(Wp + (size_t)64 * K + k0, BsD + 2048);
    __syncthreads();  // drains vmcnt -> LDS ready
    bf16x8 af[4], bfr[4];
#pragma unroll
    for (int m = 0; m < 4; ++m)
      af[m] = *(const bf16x8*)&As[(wr + m * 16 + cl) * 32 + g8];
#pragma unroll
    for (int n = 0; n < 4; ++n)
      bfr[n] = *(const bf16x8*)&Bs[(wc + n * 16 + cl) * 32 + g8];
#pragma unroll
    for (int m = 0; m < 4; ++m)
#pragma unroll
      for (int n = 0; n < 4; ++n)
        acc[m][n] = __builtin_amdgcn_mfma_f32_16x16x32_bf16(af[m], bfr[n], acc[m][n], 0, 0, 0);
  }
  const int g4 = (lane >> 4) * 4;
#pragma unroll
  for (int m = 0; m < 4; ++m)
#pragma unroll
    for (int n = 0; n < 4; ++n)
#pragma unroll
      for (int r = 0; r < 4; ++r) {
        int row = bm + wr + m * 16 + g4 + r;   // M index: b*S + s
        int col = bn + wc + n * 16 + cl;       // N index
        float fv = acc[m][n][r];
        if (EPI == 3) {
          ((float*)Cv)[(size_t)row * N + col] = fv;
        } else if (EPI == 1) {  // col = hkv*128+d -> Vt[(b*HKV+hk)*HD+d][s]
          int bb = row >> 11, s = row & (S_LEN - 1);
          int hk = col >> 7, d = col & (HD - 1);
          ((u16*)Cv)[((size_t)((bb * HKV_N + hk) * HD + d)) * S_LEN + s] = f2b(fv);
        } else {  // EPI 2: col = h*128+d -> dst[((b*HH+h)*S+s)*HD+d]
          int bb = row >> 11, s = row & (S_LEN - 1);
          int h = col >> 7, d = col & (HD - 1);
          ((u16*)Cv)[((size_t)((bb * HH + h) * S_LEN + s)) * HD + d] = f2b(fv);
        }
      }
}

// ---------------- RoPE in-place on [(b*H+h)*S+s][d] bf16 ------------------
__global__ void rope_inplace(u16* __restrict__ buf,
                             const float* __restrict__ cosT,
                             const float* __restrict__ sinT, float scale) {
  int id = blockIdx.x * blockDim.x + threadIdx.x;  // B*H*S*16 threads
  int d0 = (id & 15) * 8;
  int rs = id >> 4;                 // (b*H+h)*S + s
  int s = rs & (S_LEN - 1);
  u16* p = buf + (size_t)rs * HD + d0;
  u16x8 v = *(const u16x8*)p;
  int p0 = d0 >> 1;
  float4 c  = *(const float4*)(cosT + s * 64 + p0);
  float4 sn = *(const float4*)(sinT + s * 64 + p0);
  float cc[4] = {c.x, c.y, c.z, c.w};
  float ss[4] = {sn.x, sn.y, sn.z, sn.w};
  u16x8 o;
#pragma unroll
  for (int j = 0; j < 4; ++j) {
    float x0 = b2f(v[2 * j]), x1 = b2f(v[2 * j + 1]);
    o[2 * j]     = f2b((x0 * cc[j] - x1 * ss[j]) * scale);
    o[2 * j + 1] = f2b((x0 * ss[j] + x1 * cc[j]) * scale);
  }
  *(u16x8*)p = o;
}

// ---------------- Flash attention: 1 wave per block, KVBLK=64 -------------
// Q: [(b*HQ+h)*S+s][d] (scale pre-folded), K: [(b*HKV+hk)*S+s][d],
// Vt: [(b*HKV+hk)*HD+d][s], O: natural bf16 [b*S+q][h*HD+d]
__global__ __launch_bounds__(64, 4) void attn_fwd(const u16* __restrict__ Q,
                                                  const u16* __restrict__ Kh,
                                                  const u16* __restrict__ Vt,
                                                  u16* __restrict__ O) {
  // P split in two 16x32 panels (row stride 32 u16 = 64B, validated r5 layout)
  __shared__ alignas(16) u16 P0[16 * 32];
  __shared__ alignas(16) u16 P1[16 * 32];
  const int lane = threadIdx.x;           // 0..63
  const int bid = blockIdx.x;             // 0..4095
  const int bh = bid >> 7;                // b*HQ + h
  const int qt = 127 - (bid & 127);       // long jobs dispatched first
  const int q0 = qt * 16;
  const int bb = bh >> 4, h = bh & 15;
  const int bkv = bb * HKV_N + (h >> 1);
  const u16* Qp = Q  + ((size_t)bh * S_LEN + q0) * HD;
  const u16* Kp = Kh + (size_t)bkv * S_LEN * HD;
  const u16* Vp = Vt + (size_t)bkv * HD * S_LEN;
  const int cl = lane & 15;
  const int gr = lane >> 4;
  const int g8 = gr * 8;
  bf16x8 qf[4];
#pragma unroll
  for (int c = 0; c < 4; ++c)
    qf[c] = *(const bf16x8*)&Qp[cl * HD + c * 32 + g8];
  float m[4]    = {-1e30f, -1e30f, -1e30f, -1e30f};
  float lsum[4] = {0.f, 0.f, 0.f, 0.f};
  f32x4 oacc[8] = {};
  const int ntile = (q0 + 79) >> 6;  // 64-key tiles covering keys <= q0+15
  for (int t = 0; t < ntile; ++t) {
    const int k0 = t * 64;
    f32x4 sc[4] = {{0.f, 0.f, 0.f, 0.f}, {0.f, 0.f, 0.f, 0.f},
                   {0.f, 0.f, 0.f, 0.f}, {0.f, 0.f, 0.f, 0.f}};
    __builtin_amdgcn_s_setprio(1);
#pragma unroll
    for (int c = 0; c < 4; ++c)
#pragma unroll
      for (int ks = 0; ks < 4; ++ks) {
        bf16x8 kf = *(const bf16x8*)&Kp[(size_t)(k0 + ks * 16 + cl) * HD + c * 32 + g8];
        sc[ks] = __builtin_amdgcn_mfma_f32_16x16x32_bf16(qf[c], kf, sc[ks], 0, 0, 0);
      }
    __builtin_amdgcn_s_setprio(0);
    float corr[4];
#pragma unroll
    for (int r = 0; r < 4; ++r) {
      const int q = q0 + gr * 4 + r;
#pragma unroll
      for (int ks = 0; ks < 4; ++ks)
        if (k0 + ks * 16 + cl > q) sc[ks][r] = -1e30f;  // causal mask
      float mx = fmaxf(fmaxf(sc[0][r], sc[1][r]), fmaxf(sc[2][r], sc[3][r]));
#pragma unroll
      for (int off = 1; off < 16; off <<= 1)
        mx = fmaxf(mx, __shfl_xor(mx, off));
      const float mn = fmaxf(m[r], mx);
      corr[r] = __expf(m[r] - mn);
      float p0 = __expf(sc[0][r] - mn);
      float p1 = __expf(sc[1][r] - mn);
      float p2 = __expf(sc[2][r] - mn);
      float p3 = __expf(sc[3][r] - mn);
      float rs = (p0 + p1) + (p2 + p3);
#pragma unroll
      for (int off = 1; off < 16; off <<= 1)
        rs += __shfl_xor(rs, off);
      lsum[r] = lsum[r] * corr[r] + rs;
      m[r] = mn;
      const int row = gr * 4 + r;
      P0[row * 32 + cl]      = f2b(p0);
      P0[row * 32 + 16 + cl] = f2b(p1);
      P1[row * 32 + cl]      = f2b(p2);
      P1[row * 32 + 16 + cl] = f2b(p3);
    }
#pragma unroll
    for (int nd = 0; nd < 8; ++nd)
#pragma unroll
      for (int r = 0; r < 4; ++r) oacc[nd][r] *= corr[r];
    // within-wave LDS fence: all lanes' P writes must land before transposed read
    __builtin_amdgcn_sched_barrier(0);
    asm volatile("s_waitcnt lgkmcnt(0)" ::: "memory");
    __builtin_amdgcn_sched_barrier(0);
    bf16x8 pa0 = *(const bf16x8*)&P0[cl * 32 + g8];
    bf16x8 pa1 = *(const bf16x8*)&P1[cl * 32 + g8];
    __builtin_amdgcn_s_setprio(1);
#pragma unroll
    for (int nd = 0; nd < 8; ++nd) {
      bf16x8 vf0 = *(const bf16x8*)&Vp[(size_t)(nd * 16 + cl) * S_LEN + k0 + g8];
      bf16x8 vf1 = *(const bf16x8*)&Vp[(size_t)(nd * 16 + cl) * S_LEN + k0 + 32 + g8];
      oacc[nd] = __builtin_amdgcn_mfma_f32_16x16x32_bf16(pa0, vf0, oacc[nd], 0, 0, 0);
      oacc[nd] = __builtin_amdgcn_mfma_f32_16x16x32_bf16(pa1, vf1, oacc[nd], 0, 0, 0);
    }
    __builtin_amdgcn_s_setprio(0);
  }
#pragma unroll
  for (int r = 0; r < 4; ++r) {
    const int q = q0 + gr * 4 + r;
    const float inv = 1.0f / lsum[r];
#pragma unroll
    for (int nd = 0; nd < 8; ++nd)
      O[(((size_t)bb * S_LEN + q) * HQ_N + h) * HD + nd * 16 + cl] =
          f2b(oacc[nd][r] * inv);
  }
}

// ---------------- launch ---------------------------------------------------
extern "C" void kernel_launch(void* const* d_in, const int* in_sizes, int n_in,
                              void* d_out, int out_size, void* d_ws, size_t ws_size,
                              hipStream_t stream) {
  (void)in_sizes; (void)n_in; (void)out_size; (void)ws_size;
  const float* x  = (const float*)d_in[0];
  const float* wq = (const float*)d_in[1];
  const float* wk = (const float*)d_in[2];
  const float* wv = (const float*)d_in[3];
  const float* wo = (const float*)d_in[4];
  float* out = (float*)d_out;
  char* w = (char*)d_ws;
  // workspace map (bytes), total ~68.2 MB
  u16*  Qh   = (u16*)(w + 0);           // 16,777,216  [(b*16+h)*S+s][d]
  u16*  Kh   = (u16*)(w + 16777216);    //  8,388,608  [(b*8+hk)*S+s][d]
  u16*  Vt   = (u16*)(w + 25165824);    //  8,388,608  [(b*8+hk)*128+d][s]
  u16*  x16  = (u16*)(w + 33554432);    // 16,777,216  (attnout aliases after V gemm)
  u16*  wq16 = (u16*)(w + 50331648);    //  8,388,608  (wo16 aliases after Q gemm)
  u16*  wk16 = (u16*)(w + 58720256);    //  4,194,304
  u16*  wv16 = (u16*)(w + 62914560);    //  4,194,304
  float* cosT = (float*)(w + 67108864); //    524,288
  float* sinT = (float*)(w + 67633152); //    524,288
  u16* wo16 = wq16;                     // alias (wq16 dead after Q gemm)
  u16* attnout = x16;                   // alias (x16 dead after V gemm)

  rope_tables<<<512, 256, 0, stream>>>(cosT, sinT);
  cvt_bf16<<<4096, 256, 0, stream>>>(x,  x16);
  cvt_bf16<<<2048, 256, 0, stream>>>(wq, wq16);
  cvt_bf16<<<1024, 256, 0, stream>>>(wk, wk16);
  cvt_bf16<<<1024, 256, 0, stream>>>(wv, wv16);
  gemm_bt<2, 16><<<dim3(16, 32), 256, 0, stream>>>(x16, wq16, Qh, 4096, 2048, 2048);
  gemm_bt<2, 8> <<<dim3(8, 32),  256, 0, stream>>>(x16, wk16, Kh, 4096, 1024, 2048);
  gemm_bt<1, 8> <<<dim3(8, 32),  256, 0, stream>>>(x16, wv16, Vt, 4096, 1024, 2048);
  cvt_bf16<<<2048, 256, 0, stream>>>(wo, wo16);   // into wq16's space (dead)
  rope_inplace<<<4096, 256, 0, stream>>>(Qh, cosT, sinT, 0.08838834764831845f);
  rope_inplace<<<2048, 256, 0, stream>>>(Kh, cosT, sinT, 1.0f);
  attn_fwd<<<4096, 64, 0, stream>>>(Qh, Kh, Vt, attnout);
  gemm_bt<3, 16><<<dim3(16, 32), 256, 0, stream>>>(attnout, wo16, out, 4096, 2048, 2048);
}

// Round 7
// 486.010 us; speedup vs baseline: 1.6268x; 1.6268x over previous
//
#include <hip/hip_runtime.h>

// Problem constants
#define S_LEN 2048
#define DM    2048
#define HQ_N  16
#define HKV_N 8
#define HD    128

typedef unsigned short u16;
typedef unsigned int   u32;
typedef short bf16x8 __attribute__((ext_vector_type(8)));
typedef float f32x4  __attribute__((ext_vector_type(4)));
typedef u16   u16x8  __attribute__((ext_vector_type(8)));

__device__ __forceinline__ float b2f(u16 u) {
  u32 x = ((u32)u) << 16;
  return __builtin_bit_cast(float, x);
}
__device__ __forceinline__ u16 f2b(float f) {  // RNE
  u32 u = __builtin_bit_cast(u32, f);
  u32 r = u + 0x7fffu + ((u >> 16) & 1u);
  return (u16)(r >> 16);
}

// direct global->LDS DMA, 16B per lane (dest = wave-uniform base + lane*16)
#define GLOAD_LDS16(g, l)                                                     \
  __builtin_amdgcn_global_load_lds(                                           \
      (const __attribute__((address_space(1))) void*)(g),                     \
      (__attribute__((address_space(3))) void*)(l), 16, 0, 0)

// ---------------- f32 -> bf16 bulk convert (8 elems/thread) ---------------
__global__ void cvt_bf16(const float* __restrict__ src, u16* __restrict__ dst) {
  int id = blockIdx.x * blockDim.x + threadIdx.x;
  float4 a = ((const float4*)src)[id * 2];
  float4 b = ((const float4*)src)[id * 2 + 1];
  u16x8 o;
  o[0] = f2b(a.x); o[1] = f2b(a.y); o[2] = f2b(a.z); o[3] = f2b(a.w);
  o[4] = f2b(b.x); o[5] = f2b(b.y); o[6] = f2b(b.z); o[7] = f2b(b.w);
  ((u16x8*)dst)[id] = o;
}

// ---------------- RoPE tables: cos/sin[t][i], t<2048, i<64 ----------------
__global__ void rope_tables(float* __restrict__ cosT, float* __restrict__ sinT) {
  int id = blockIdx.x * blockDim.x + threadIdx.x;  // 131072
  int t = id >> 6, i = id & 63;
  float inv = (float)pow(10000.0, -(double)(2 * i) / 128.0);
  float ang = (float)t * inv;
  cosT[id] = cosf(ang);
  sinT[id] = sinf(ang);
}

// ---------------- GEMM: C(MxN) = A(MxK) * W(NxK)^T, bf16 in, f32 acc ------
// Staging via global_load_lds width=16 (m97 pattern).
// EPI 1: V-transpose -> Vt[(b*HKV+hk)*HD+d][s] bf16
// EPI 2: head-transpose -> dst[((b*HH+h)*S+s)*HD+d] bf16
// EPI 3: natural f32 (final output)
template <int EPI, int HH>
__global__ __launch_bounds__(256) void gemm_bt(const u16* __restrict__ A,
                                               const u16* __restrict__ W,
                                               void* __restrict__ Cv,
                                               int M, int N, int K) {
  __shared__ alignas(16) u16 As[128 * 32];
  __shared__ alignas(16) u16 Bs[128 * 32];
  const int tid  = threadIdx.x;
  const int lane = tid & 63;
  const int wave = tid >> 6;
  const int wr = (wave >> 1) * 64;  // wave row offset in tile
  const int wc = (wave & 1) * 64;   // wave col offset in tile
  const int bm = blockIdx.y * 128;
  const int bn = blockIdx.x * 128;
  const int r0 = tid >> 2;          // staging row 0..63
  const int c0 = (tid & 3) * 8;     // staging col {0,8,16,24}
  u16* AsD = &As[tid * 8];
  u16* BsD = &Bs[tid * 8];
  const u16* Ap = A + (size_t)(bm + r0) * K + c0;
  const u16* Wp = W + (size_t)(bn + r0) * K + c0;
  const int cl = lane & 15;
  const int g8 = (lane >> 4) * 8;
  f32x4 acc[4][4] = {};
  for (int k0 = 0; k0 < K; k0 += 32) {
    __syncthreads();  // previous iteration's readers done
    GLOAD_LDS16(Ap + k0, AsD);
    GLOAD_LDS16(Ap + (size_t)64 * K + k0, AsD + 2048);
    GLOAD_LDS16(Wp + k0, BsD);
    GLOAD_LDS16(Wp + (size_t)64 * K + k0, BsD + 2048);
    __syncthreads();  // drains vmcnt -> LDS ready
    bf16x8 af[4], bfr[4];
#pragma unroll
    for (int m = 0; m < 4; ++m)
      af[m] = *(const bf16x8*)&As[(wr + m * 16 + cl) * 32 + g8];
#pragma unroll
    for (int n = 0; n < 4; ++n)
      bfr[n] = *(const bf16x8*)&Bs[(wc + n * 16 + cl) * 32 + g8];
#pragma unroll
    for (int m = 0; m < 4; ++m)
#pragma unroll
      for (int n = 0; n < 4; ++n)
        acc[m][n] = __builtin_amdgcn_mfma_f32_16x16x32_bf16(af[m], bfr[n], acc[m][n], 0, 0, 0);
  }
  const int g4 = (lane >> 4) * 4;
#pragma unroll
  for (int m = 0; m < 4; ++m)
#pragma unroll
    for (int n = 0; n < 4; ++n)
#pragma unroll
      for (int r = 0; r < 4; ++r) {
        int row = bm + wr + m * 16 + g4 + r;   // M index: b*S + s
        int col = bn + wc + n * 16 + cl;       // N index
        float fv = acc[m][n][r];
        if (EPI == 3) {
          ((float*)Cv)[(size_t)row * N + col] = fv;
        } else if (EPI == 1) {  // col = hkv*128+d -> Vt[(b*HKV+hk)*HD+d][s]
          int bb = row >> 11, s = row & (S_LEN - 1);
          int hk = col >> 7, d = col & (HD - 1);
          ((u16*)Cv)[((size_t)((bb * HKV_N + hk) * HD + d)) * S_LEN + s] = f2b(fv);
        } else {  // EPI 2: col = h*128+d -> dst[((b*HH+h)*S+s)*HD+d]
          int bb = row >> 11, s = row & (S_LEN - 1);
          int h = col >> 7, d = col & (HD - 1);
          ((u16*)Cv)[((size_t)((bb * HH + h) * S_LEN + s)) * HD + d] = f2b(fv);
        }
      }
}

// ---------------- RoPE in-place on [(b*H+h)*S+s][d] bf16 ------------------
__global__ void rope_inplace(u16* __restrict__ buf,
                             const float* __restrict__ cosT,
                             const float* __restrict__ sinT, float scale) {
  int id = blockIdx.x * blockDim.x + threadIdx.x;  // B*H*S*16 threads
  int d0 = (id & 15) * 8;
  int rs = id >> 4;                 // (b*H+h)*S + s
  int s = rs & (S_LEN - 1);
  u16* p = buf + (size_t)rs * HD + d0;
  u16x8 v = *(const u16x8*)p;
  int p0 = d0 >> 1;
  float4 c  = *(const float4*)(cosT + s * 64 + p0);
  float4 sn = *(const float4*)(sinT + s * 64 + p0);
  float cc[4] = {c.x, c.y, c.z, c.w};
  float ss[4] = {sn.x, sn.y, sn.z, sn.w};
  u16x8 o;
#pragma unroll
  for (int j = 0; j < 4; ++j) {
    float x0 = b2f(v[2 * j]), x1 = b2f(v[2 * j + 1]);
    o[2 * j]     = f2b((x0 * cc[j] - x1 * ss[j]) * scale);
    o[2 * j + 1] = f2b((x0 * ss[j] + x1 * cc[j]) * scale);
  }
  *(u16x8*)p = o;
}

// ---------------- Flash attention: 64-row Q block, LDS-staged K/V ---------
// Q: [(b*HQ+h)*S+s][d] (scale pre-folded), K: [(b*HKV+hk)*S+s][d],
// Vt: [(b*HKV+hk)*HD+d][s], O: natural bf16 [b*S+q][h*HD+d]
// 1024 blocks x 256 thr. Block = (bh, qblk): 64 Q rows, tiles of 64 keys.
// K/V staged to LDS via global_load_lds with XOR-swizzled source (T2/r21).
__global__ __launch_bounds__(256, 4) void attn_fwd(const u16* __restrict__ Q,
                                                   const u16* __restrict__ Kh,
                                                   const u16* __restrict__ Vt,
                                                   u16* __restrict__ O) {
  __shared__ alignas(16) u16 Ks[64 * 128];      // [key][d], cols XOR-swizzled
  __shared__ alignas(16) u16 Vs[128 * 64];      // [d][key], cols XOR-swizzled
  __shared__ alignas(16) u16 Plds[4][2][16 * 32];
  const int tid  = threadIdx.x;
  const int wave = tid >> 6;
  const int lane = tid & 63;
  // XCD-grouped bijective remap: 128 consecutive orig per XCD (1024%8==0)
  const int orig = (blockIdx.x & 7) * 128 + (blockIdx.x >> 3);
  const int bh = orig >> 5;                 // b*HQ + h
  const int j = orig & 31;
  const int qblk = (j & 1) ? ((j - 1) >> 1) : (31 - (j >> 1));  // (31,0),(30,1)..
  const int bb = bh >> 4, h = bh & 15;
  const int bkv = bb * HKV_N + (h >> 1);
  const u16* Kp = Kh + (size_t)bkv * S_LEN * HD;
  const u16* Vp = Vt + (size_t)bkv * HD * S_LEN;
  const int cl = lane & 15;
  const int gr = lane >> 4;
  const int g8 = gr * 8;
  const int sw8 = (cl & 7) << 3;            // read-side XOR (u16 units)
  // Q fragments (16 rows per wave)
  const int q0w = qblk * 64 + wave * 16;
  const u16* Qp = Q + ((size_t)bh * S_LEN + q0w) * HD;
  bf16x8 qf[4];
#pragma unroll
  for (int c = 0; c < 4; ++c)
    qf[c] = *(const bf16x8*)&Qp[cl * HD + c * 32 + g8];
  // staging source addrs (pre-swizzled so linear LDS dest == swizzled layout)
  // K instr (wave,j2): LDS rows j2*16+wave*4+gr, row-swz = (wave*4+gr)&7
  const int krow_w = wave * 4 + gr;
  const int kcol = (cl * 8) ^ ((krow_w & 7) << 3);
  const u16* kSrc = Kp + (size_t)krow_w * HD + kcol;
  // V instr (wave,j2): LDS d-rows j2*32+wave*8+(lane>>3), row-swz = (lane>>3)&7
  const int vrow_w = wave * 8 + (lane >> 3);
  const int vcol = ((lane & 7) * 8) ^ (((lane >> 3) & 7) << 3);
  const u16* vSrc = Vp + (size_t)vrow_w * S_LEN + vcol;
  float m[4]    = {-1e30f, -1e30f, -1e30f, -1e30f};
  float lsum[4] = {0.f, 0.f, 0.f, 0.f};
  f32x4 oacc[8] = {};
  u16* Pw0 = &Plds[wave][0][0];
  u16* Pw1 = &Plds[wave][1][0];
  for (int t = 0; t <= qblk; ++t) {
    const int k0 = t * 64;
    __syncthreads();  // previous tile's readers done
#pragma unroll
    for (int j2 = 0; j2 < 4; ++j2)
      GLOAD_LDS16(kSrc + (size_t)(k0 + j2 * 16) * HD, &Ks[(j2 * 4 + wave) * 512]);
#pragma unroll
    for (int j2 = 0; j2 < 4; ++j2)
      GLOAD_LDS16(vSrc + (size_t)j2 * 32 * S_LEN + k0, &Vs[(j2 * 4 + wave) * 512]);
    __syncthreads();  // vmcnt drained at barrier -> LDS ready
    // QK^T from LDS
    f32x4 sc[4] = {{0.f, 0.f, 0.f, 0.f}, {0.f, 0.f, 0.f, 0.f},
                   {0.f, 0.f, 0.f, 0.f}, {0.f, 0.f, 0.f, 0.f}};
#pragma unroll
    for (int c = 0; c < 4; ++c) {
      const int kq = (c * 32 + g8) ^ sw8;
#pragma unroll
      for (int ks = 0; ks < 4; ++ks) {
        bf16x8 kf = *(const bf16x8*)&Ks[(ks * 16 + cl) * 128 + kq];
        sc[ks] = __builtin_amdgcn_mfma_f32_16x16x32_bf16(qf[c], kf, sc[ks], 0, 0, 0);
      }
    }
    // online softmax (mask only on the diagonal tile)
    float corr[4];
    if (t == qblk) {
#pragma unroll
      for (int r = 0; r < 4; ++r) {
        const int qrel = wave * 16 + gr * 4 + r;  // q - 64*qblk
#pragma unroll
        for (int ks = 0; ks < 4; ++ks)
          if (ks * 16 + cl > qrel) sc[ks][r] = -1e30f;
      }
    }
#pragma unroll
    for (int r = 0; r < 4; ++r) {
      float mx = fmaxf(fmaxf(sc[0][r], sc[1][r]), fmaxf(sc[2][r], sc[3][r]));
#pragma unroll
      for (int off = 1; off < 16; off <<= 1)
        mx = fmaxf(mx, __shfl_xor(mx, off));
      const float mn = fmaxf(m[r], mx);
      corr[r] = __expf(m[r] - mn);
      float p0 = __expf(sc[0][r] - mn);
      float p1 = __expf(sc[1][r] - mn);
      float p2 = __expf(sc[2][r] - mn);
      float p3 = __expf(sc[3][r] - mn);
      float rs = (p0 + p1) + (p2 + p3);
#pragma unroll
      for (int off = 1; off < 16; off <<= 1)
        rs += __shfl_xor(rs, off);
      lsum[r] = lsum[r] * corr[r] + rs;
      m[r] = mn;
      const int row = gr * 4 + r;
      Pw0[row * 32 + cl]      = f2b(p0);
      Pw0[row * 32 + 16 + cl] = f2b(p1);
      Pw1[row * 32 + cl]      = f2b(p2);
      Pw1[row * 32 + 16 + cl] = f2b(p3);
    }
#pragma unroll
    for (int nd = 0; nd < 8; ++nd)
#pragma unroll
      for (int r = 0; r < 4; ++r) oacc[nd][r] *= corr[r];
    // within-wave LDS fence: all lanes' P writes land before transposed read
    __builtin_amdgcn_sched_barrier(0);
    asm volatile("s_waitcnt lgkmcnt(0)" ::: "memory");
    __builtin_amdgcn_sched_barrier(0);
    bf16x8 pa0 = *(const bf16x8*)&Pw0[cl * 32 + g8];
    bf16x8 pa1 = *(const bf16x8*)&Pw1[cl * 32 + g8];
    // PV from LDS (V pre-transposed: rows = d, cols = keys)
    const int vq0 = g8 ^ sw8;
    const int vq1 = (32 + g8) ^ sw8;
#pragma unroll
    for (int nd = 0; nd < 8; ++nd) {
      bf16x8 vf0 = *(const bf16x8*)&Vs[(nd * 16 + cl) * 64 + vq0];
      bf16x8 vf1 = *(const bf16x8*)&Vs[(nd * 16 + cl) * 64 + vq1];
      oacc[nd] = __builtin_amdgcn_mfma_f32_16x16x32_bf16(pa0, vf0, oacc[nd], 0, 0, 0);
      oacc[nd] = __builtin_amdgcn_mfma_f32_16x16x32_bf16(pa1, vf1, oacc[nd], 0, 0, 0);
    }
  }
#pragma unroll
  for (int r = 0; r < 4; ++r) {
    const int q = q0w + gr * 4 + r;
    const float inv = 1.0f / lsum[r];
#pragma unroll
    for (int nd = 0; nd < 8; ++nd)
      O[(((size_t)bb * S_LEN + q) * HQ_N + h) * HD + nd * 16 + cl] =
          f2b(oacc[nd][r] * inv);
  }
}

// ---------------- launch ---------------------------------------------------
extern "C" void kernel_launch(void* const* d_in, const int* in_sizes, int n_in,
                              void* d_out, int out_size, void* d_ws, size_t ws_size,
                              hipStream_t stream) {
  (void)in_sizes; (void)n_in; (void)out_size; (void)ws_size;
  const float* x  = (const float*)d_in[0];
  const float* wq = (const float*)d_in[1];
  const float* wk = (const float*)d_in[2];
  const float* wv = (const float*)d_in[3];
  const float* wo = (const float*)d_in[4];
  float* out = (float*)d_out;
  char* w = (char*)d_ws;
  // workspace map (bytes), total ~68.2 MB
  u16*  Qh   = (u16*)(w + 0);           // 16,777,216  [(b*16+h)*S+s][d]
  u16*  Kh   = (u16*)(w + 16777216);    //  8,388,608  [(b*8+hk)*S+s][d]
  u16*  Vt   = (u16*)(w + 25165824);    //  8,388,608  [(b*8+hk)*128+d][s]
  u16*  x16  = (u16*)(w + 33554432);    // 16,777,216  (attnout aliases after V gemm)
  u16*  wq16 = (u16*)(w + 50331648);    //  8,388,608  (wo16 aliases after Q gemm)
  u16*  wk16 = (u16*)(w + 58720256);    //  4,194,304
  u16*  wv16 = (u16*)(w + 62914560);    //  4,194,304
  float* cosT = (float*)(w + 67108864); //    524,288
  float* sinT = (float*)(w + 67633152); //    524,288
  u16* wo16 = wq16;                     // alias (wq16 dead after Q gemm)
  u16* attnout = x16;                   // alias (x16 dead after V gemm)

  rope_tables<<<512, 256, 0, stream>>>(cosT, sinT);
  cvt_bf16<<<4096, 256, 0, stream>>>(x,  x16);
  cvt_bf16<<<2048, 256, 0, stream>>>(wq, wq16);
  cvt_bf16<<<1024, 256, 0, stream>>>(wk, wk16);
  cvt_bf16<<<1024, 256, 0, stream>>>(wv, wv16);
  gemm_bt<2, 16><<<dim3(16, 32), 256, 0, stream>>>(x16, wq16, Qh, 4096, 2048, 2048);
  gemm_bt<2, 8> <<<dim3(8, 32),  256, 0, stream>>>(x16, wk16, Kh, 4096, 1024, 2048);
  gemm_bt<1, 8> <<<dim3(8, 32),  256, 0, stream>>>(x16, wv16, Vt, 4096, 1024, 2048);
  cvt_bf16<<<2048, 256, 0, stream>>>(wo, wo16);   // into wq16's space (dead)
  rope_inplace<<<4096, 256, 0, stream>>>(Qh, cosT, sinT, 0.08838834764831845f);
  rope_inplace<<<2048, 256, 0, stream>>>(Kh, cosT, sinT, 1.0f);
  attn_fwd<<<1024, 256, 0, stream>>>(Qh, Kh, Vt, attnout);
  gemm_bt<3, 16><<<dim3(16, 32), 256, 0, stream>>>(attnout, wo16, out, 4096, 2048, 2048);
}

// Round 8
// 455.279 us; speedup vs baseline: 1.7366x; 1.0675x over previous
//
#include <hip/hip_runtime.h>

// Problem constants
#define S_LEN 2048
#define DM    2048
#define HQ_N  16
#define HKV_N 8
#define HD    128

typedef unsigned short u16;
typedef unsigned int   u32;
typedef short bf16x8 __attribute__((ext_vector_type(8)));
typedef float f32x4  __attribute__((ext_vector_type(4)));
typedef u16   u16x8  __attribute__((ext_vector_type(8)));

__device__ __forceinline__ float b2f(u16 u) {
  u32 x = ((u32)u) << 16;
  return __builtin_bit_cast(float, x);
}
__device__ __forceinline__ u16 f2b(float f) {  // RNE
  u32 u = __builtin_bit_cast(u32, f);
  u32 r = u + 0x7fffu + ((u >> 16) & 1u);
  return (u16)(r >> 16);
}

// direct global->LDS DMA, 16B per lane (dest = wave-uniform base + lane*16)
#define GLOAD_LDS16(g, l)                                                     \
  __builtin_amdgcn_global_load_lds(                                           \
      (const __attribute__((address_space(1))) void*)(g),                     \
      (__attribute__((address_space(3))) void*)(l), 16, 0, 0)

// ---------------- f32 -> bf16 bulk convert (8 elems/thread) ---------------
__global__ void cvt_bf16(const float* __restrict__ src, u16* __restrict__ dst) {
  int id = blockIdx.x * blockDim.x + threadIdx.x;
  float4 a = ((const float4*)src)[id * 2];
  float4 b = ((const float4*)src)[id * 2 + 1];
  u16x8 o;
  o[0] = f2b(a.x); o[1] = f2b(a.y); o[2] = f2b(a.z); o[3] = f2b(a.w);
  o[4] = f2b(b.x); o[5] = f2b(b.y); o[6] = f2b(b.z); o[7] = f2b(b.w);
  ((u16x8*)dst)[id] = o;
}

// ---------------- RoPE tables: cos/sin[t][i], t<2048, i<64 ----------------
__global__ void rope_tables(float* __restrict__ cosT, float* __restrict__ sinT) {
  int id = blockIdx.x * blockDim.x + threadIdx.x;  // 131072
  int t = id >> 6, i = id & 63;
  float inv = (float)pow(10000.0, -(double)(2 * i) / 128.0);
  float ang = (float)t * inv;
  cosT[id] = cosf(ang);
  sinT[id] = sinf(ang);
}

// ---------------- Fused QKV GEMM: C(4096x4096) = x16 * wqkv^T -------------
// A: x16 [b*S+s][2048], W: wqkv [n][2048] (wq rows 0-2047, wk 2048-3071,
// wv 3072-4095). Epilogue routes per-region:
//   cols 0-2047  -> Qh[((b*16+h)*S+s)*128+d]    (head-transposed)
//   cols 2048-.. -> Kh[((b*8+hk)*S+s)*128+d]
//   cols 3072-.. -> Vt[((b*8+hk)*128+d)*S+s]    (V transposed for PV)
// 1024 blocks, XCD-grouped remap (1024%8==0 -> bijective).
__global__ __launch_bounds__(256) void gemm_qkv(const u16* __restrict__ A,
                                                const u16* __restrict__ W,
                                                u16* __restrict__ Qh,
                                                u16* __restrict__ Kh,
                                                u16* __restrict__ Vt) {
  __shared__ alignas(16) u16 As[128 * 32];
  __shared__ alignas(16) u16 Bs[128 * 32];
  const int K = DM;
  const int tid  = threadIdx.x;
  const int lane = tid & 63;
  const int wave = tid >> 6;
  const int wr = (wave >> 1) * 64;
  const int wc = (wave & 1) * 64;
  // XCD-grouped bijective remap; bn-major chunks -> 4 B-panels per XCD L2
  const int orig = (blockIdx.x & 7) * 128 + (blockIdx.x >> 3);
  const int bn = (orig >> 5) * 128;
  const int bm = (orig & 31) * 128;
  const int r0 = tid >> 2;
  const int c0 = (tid & 3) * 8;
  u16* AsD = &As[tid * 8];
  u16* BsD = &Bs[tid * 8];
  const u16* Ap = A + (size_t)(bm + r0) * K + c0;
  const u16* Wp = W + (size_t)(bn + r0) * K + c0;
  const int cl = lane & 15;
  const int g8 = (lane >> 4) * 8;
  f32x4 acc[4][4] = {};
  for (int k0 = 0; k0 < K; k0 += 32) {
    __syncthreads();
    GLOAD_LDS16(Ap + k0, AsD);
    GLOAD_LDS16(Ap + (size_t)64 * K + k0, AsD + 2048);
    GLOAD_LDS16(Wp + k0, BsD);
    GLOAD_LDS16(Wp + (size_t)64 * K + k0, BsD + 2048);
    __syncthreads();
    bf16x8 af[4], bfr[4];
#pragma unroll
    for (int m = 0; m < 4; ++m)
      af[m] = *(const bf16x8*)&As[(wr + m * 16 + cl) * 32 + g8];
#pragma unroll
    for (int n = 0; n < 4; ++n)
      bfr[n] = *(const bf16x8*)&Bs[(wc + n * 16 + cl) * 32 + g8];
#pragma unroll
    for (int m = 0; m < 4; ++m)
#pragma unroll
      for (int n = 0; n < 4; ++n)
        acc[m][n] = __builtin_amdgcn_mfma_f32_16x16x32_bf16(af[m], bfr[n], acc[m][n], 0, 0, 0);
  }
  const int g4 = (lane >> 4) * 4;
#pragma unroll
  for (int m = 0; m < 4; ++m)
#pragma unroll
    for (int n = 0; n < 4; ++n)
#pragma unroll
      for (int r = 0; r < 4; ++r) {
        int row = bm + wr + m * 16 + g4 + r;   // b*S + s
        int col = bn + wc + n * 16 + cl;       // 0..4095
        int bb = row >> 11, s = row & (S_LEN - 1);
        u16 v = f2b(acc[m][n][r]);
        if (bn < 2048) {        // Q
          int h = col >> 7, d = col & (HD - 1);
          Qh[((size_t)((bb * HQ_N + h) * S_LEN + s)) * HD + d] = v;
        } else if (bn < 3072) { // K
          int hk = (col >> 7) - 16, d = col & (HD - 1);
          Kh[((size_t)((bb * HKV_N + hk) * S_LEN + s)) * HD + d] = v;
        } else {                // V -> transposed
          int hk = (col >> 7) - 24, d = col & (HD - 1);
          Vt[((size_t)((bb * HKV_N + hk) * HD + d)) * S_LEN + s] = v;
        }
      }
}

// ---------------- Output GEMM: out(4096x2048 f32) = attnout * wo^T --------
__global__ __launch_bounds__(256) void gemm_out(const u16* __restrict__ A,
                                                const u16* __restrict__ W,
                                                float* __restrict__ C,
                                                int M, int N, int K) {
  __shared__ alignas(16) u16 As[128 * 32];
  __shared__ alignas(16) u16 Bs[128 * 32];
  const int tid  = threadIdx.x;
  const int lane = tid & 63;
  const int wave = tid >> 6;
  const int wr = (wave >> 1) * 64;
  const int wc = (wave & 1) * 64;
  const int bm = blockIdx.y * 128;
  const int bn = blockIdx.x * 128;
  const int r0 = tid >> 2;
  const int c0 = (tid & 3) * 8;
  u16* AsD = &As[tid * 8];
  u16* BsD = &Bs[tid * 8];
  const u16* Ap = A + (size_t)(bm + r0) * K + c0;
  const u16* Wp = W + (size_t)(bn + r0) * K + c0;
  const int cl = lane & 15;
  const int g8 = (lane >> 4) * 8;
  f32x4 acc[4][4] = {};
  for (int k0 = 0; k0 < K; k0 += 32) {
    __syncthreads();
    GLOAD_LDS16(Ap + k0, AsD);
    GLOAD_LDS16(Ap + (size_t)64 * K + k0, AsD + 2048);
    GLOAD_LDS16(Wp + k0, BsD);
    GLOAD_LDS16(Wp + (size_t)64 * K + k0, BsD + 2048);
    __syncthreads();
    bf16x8 af[4], bfr[4];
#pragma unroll
    for (int m = 0; m < 4; ++m)
      af[m] = *(const bf16x8*)&As[(wr + m * 16 + cl) * 32 + g8];
#pragma unroll
    for (int n = 0; n < 4; ++n)
      bfr[n] = *(const bf16x8*)&Bs[(wc + n * 16 + cl) * 32 + g8];
#pragma unroll
    for (int m = 0; m < 4; ++m)
#pragma unroll
      for (int n = 0; n < 4; ++n)
        acc[m][n] = __builtin_amdgcn_mfma_f32_16x16x32_bf16(af[m], bfr[n], acc[m][n], 0, 0, 0);
  }
  const int g4 = (lane >> 4) * 4;
#pragma unroll
  for (int m = 0; m < 4; ++m)
#pragma unroll
    for (int n = 0; n < 4; ++n)
#pragma unroll
      for (int r = 0; r < 4; ++r) {
        int row = bm + wr + m * 16 + g4 + r;
        int col = bn + wc + n * 16 + cl;
        C[(size_t)row * N + col] = acc[m][n][r];
      }
}

// ---------------- RoPE in-place on [(b*H+h)*S+s][d] bf16 ------------------
__global__ void rope_inplace(u16* __restrict__ buf,
                             const float* __restrict__ cosT,
                             const float* __restrict__ sinT, float scale) {
  int id = blockIdx.x * blockDim.x + threadIdx.x;  // B*H*S*16 threads
  int d0 = (id & 15) * 8;
  int rs = id >> 4;                 // (b*H+h)*S + s
  int s = rs & (S_LEN - 1);
  u16* p = buf + (size_t)rs * HD + d0;
  u16x8 v = *(const u16x8*)p;
  int p0 = d0 >> 1;
  float4 c  = *(const float4*)(cosT + s * 64 + p0);
  float4 sn = *(const float4*)(sinT + s * 64 + p0);
  float cc[4] = {c.x, c.y, c.z, c.w};
  float ss[4] = {sn.x, sn.y, sn.z, sn.w};
  u16x8 o;
#pragma unroll
  for (int j = 0; j < 4; ++j) {
    float x0 = b2f(v[2 * j]), x1 = b2f(v[2 * j + 1]);
    o[2 * j]     = f2b((x0 * cc[j] - x1 * ss[j]) * scale);
    o[2 * j + 1] = f2b((x0 * ss[j] + x1 * cc[j]) * scale);
  }
  *(u16x8*)p = o;
}

// ---------------- Flash attention: 64-row Q block, LDS-staged K/V ---------
// (unchanged from round 7 — 154 us, verified)
__global__ __launch_bounds__(256, 4) void attn_fwd(const u16* __restrict__ Q,
                                                   const u16* __restrict__ Kh,
                                                   const u16* __restrict__ Vt,
                                                   u16* __restrict__ O) {
  __shared__ alignas(16) u16 Ks[64 * 128];      // [key][d], cols XOR-swizzled
  __shared__ alignas(16) u16 Vs[128 * 64];      // [d][key], cols XOR-swizzled
  __shared__ alignas(16) u16 Plds[4][2][16 * 32];
  const int tid  = threadIdx.x;
  const int wave = tid >> 6;
  const int lane = tid & 63;
  const int orig = (blockIdx.x & 7) * 128 + (blockIdx.x >> 3);
  const int bh = orig >> 5;                 // b*HQ + h
  const int j = orig & 31;
  const int qblk = (j & 1) ? ((j - 1) >> 1) : (31 - (j >> 1));
  const int bb = bh >> 4, h = bh & 15;
  const int bkv = bb * HKV_N + (h >> 1);
  const u16* Kp = Kh + (size_t)bkv * S_LEN * HD;
  const u16* Vp = Vt + (size_t)bkv * HD * S_LEN;
  const int cl = lane & 15;
  const int gr = lane >> 4;
  const int g8 = gr * 8;
  const int sw8 = (cl & 7) << 3;
  const int q0w = qblk * 64 + wave * 16;
  const u16* Qp = Q + ((size_t)bh * S_LEN + q0w) * HD;
  bf16x8 qf[4];
#pragma unroll
  for (int c = 0; c < 4; ++c)
    qf[c] = *(const bf16x8*)&Qp[cl * HD + c * 32 + g8];
  const int krow_w = wave * 4 + gr;
  const int kcol = (cl * 8) ^ ((krow_w & 7) << 3);
  const u16* kSrc = Kp + (size_t)krow_w * HD + kcol;
  const int vrow_w = wave * 8 + (lane >> 3);
  const int vcol = ((lane & 7) * 8) ^ (((lane >> 3) & 7) << 3);
  const u16* vSrc = Vp + (size_t)vrow_w * S_LEN + vcol;
  float m[4]    = {-1e30f, -1e30f, -1e30f, -1e30f};
  float lsum[4] = {0.f, 0.f, 0.f, 0.f};
  f32x4 oacc[8] = {};
  u16* Pw0 = &Plds[wave][0][0];
  u16* Pw1 = &Plds[wave][1][0];
  for (int t = 0; t <= qblk; ++t) {
    const int k0 = t * 64;
    __syncthreads();
#pragma unroll
    for (int j2 = 0; j2 < 4; ++j2)
      GLOAD_LDS16(kSrc + (size_t)(k0 + j2 * 16) * HD, &Ks[(j2 * 4 + wave) * 512]);
#pragma unroll
    for (int j2 = 0; j2 < 4; ++j2)
      GLOAD_LDS16(vSrc + (size_t)j2 * 32 * S_LEN + k0, &Vs[(j2 * 4 + wave) * 512]);
    __syncthreads();
    f32x4 sc[4] = {{0.f, 0.f, 0.f, 0.f}, {0.f, 0.f, 0.f, 0.f},
                   {0.f, 0.f, 0.f, 0.f}, {0.f, 0.f, 0.f, 0.f}};
#pragma unroll
    for (int c = 0; c < 4; ++c) {
      const int kq = (c * 32 + g8) ^ sw8;
#pragma unroll
      for (int ks = 0; ks < 4; ++ks) {
        bf16x8 kf = *(const bf16x8*)&Ks[(ks * 16 + cl) * 128 + kq];
        sc[ks] = __builtin_amdgcn_mfma_f32_16x16x32_bf16(qf[c], kf, sc[ks], 0, 0, 0);
      }
    }
    float corr[4];
    if (t == qblk) {
#pragma unroll
      for (int r = 0; r < 4; ++r) {
        const int qrel = wave * 16 + gr * 4 + r;
#pragma unroll
        for (int ks = 0; ks < 4; ++ks)
          if (ks * 16 + cl > qrel) sc[ks][r] = -1e30f;
      }
    }
#pragma unroll
    for (int r = 0; r < 4; ++r) {
      float mx = fmaxf(fmaxf(sc[0][r], sc[1][r]), fmaxf(sc[2][r], sc[3][r]));
#pragma unroll
      for (int off = 1; off < 16; off <<= 1)
        mx = fmaxf(mx, __shfl_xor(mx, off));
      const float mn = fmaxf(m[r], mx);
      corr[r] = __expf(m[r] - mn);
      float p0 = __expf(sc[0][r] - mn);
      float p1 = __expf(sc[1][r] - mn);
      float p2 = __expf(sc[2][r] - mn);
      float p3 = __expf(sc[3][r] - mn);
      float rs = (p0 + p1) + (p2 + p3);
#pragma unroll
      for (int off = 1; off < 16; off <<= 1)
        rs += __shfl_xor(rs, off);
      lsum[r] = lsum[r] * corr[r] + rs;
      m[r] = mn;
      const int row = gr * 4 + r;
      Pw0[row * 32 + cl]      = f2b(p0);
      Pw0[row * 32 + 16 + cl] = f2b(p1);
      Pw1[row * 32 + cl]      = f2b(p2);
      Pw1[row * 32 + 16 + cl] = f2b(p3);
    }
#pragma unroll
    for (int nd = 0; nd < 8; ++nd)
#pragma unroll
      for (int r = 0; r < 4; ++r) oacc[nd][r] *= corr[r];
    __builtin_amdgcn_sched_barrier(0);
    asm volatile("s_waitcnt lgkmcnt(0)" ::: "memory");
    __builtin_amdgcn_sched_barrier(0);
    bf16x8 pa0 = *(const bf16x8*)&Pw0[cl * 32 + g8];
    bf16x8 pa1 = *(const bf16x8*)&Pw1[cl * 32 + g8];
    const int vq0 = g8 ^ sw8;
    const int vq1 = (32 + g8) ^ sw8;
#pragma unroll
    for (int nd = 0; nd < 8; ++nd) {
      bf16x8 vf0 = *(const bf16x8*)&Vs[(nd * 16 + cl) * 64 + vq0];
      bf16x8 vf1 = *(const bf16x8*)&Vs[(nd * 16 + cl) * 64 + vq1];
      oacc[nd] = __builtin_amdgcn_mfma_f32_16x16x32_bf16(pa0, vf0, oacc[nd], 0, 0, 0);
      oacc[nd] = __builtin_amdgcn_mfma_f32_16x16x32_bf16(pa1, vf1, oacc[nd], 0, 0, 0);
    }
  }
#pragma unroll
  for (int r = 0; r < 4; ++r) {
    const int q = q0w + gr * 4 + r;
    const float inv = 1.0f / lsum[r];
#pragma unroll
    for (int nd = 0; nd < 8; ++nd)
      O[(((size_t)bb * S_LEN + q) * HQ_N + h) * HD + nd * 16 + cl] =
          f2b(oacc[nd][r] * inv);
  }
}

// ---------------- launch ---------------------------------------------------
extern "C" void kernel_launch(void* const* d_in, const int* in_sizes, int n_in,
                              void* d_out, int out_size, void* d_ws, size_t ws_size,
                              hipStream_t stream) {
  (void)in_sizes; (void)n_in; (void)out_size; (void)ws_size;
  const float* x  = (const float*)d_in[0];
  const float* wq = (const float*)d_in[1];
  const float* wk = (const float*)d_in[2];
  const float* wv = (const float*)d_in[3];
  const float* wo = (const float*)d_in[4];
  float* out = (float*)d_out;
  char* w = (char*)d_ws;
  // workspace map (bytes), total ~68.2 MB
  u16*  Qh     = (u16*)(w + 0);           // 16,777,216  [(b*16+h)*S+s][d]
  u16*  Kh     = (u16*)(w + 16777216);    //  8,388,608  [(b*8+hk)*S+s][d]
  u16*  Vt     = (u16*)(w + 25165824);    //  8,388,608  [(b*8+hk)*128+d][s]
  u16*  x16    = (u16*)(w + 33554432);    // 16,777,216  (attnout alias after QKV)
  u16*  wqkv16 = (u16*)(w + 50331648);    // 16,777,216  [wq;wk;wv] rows x 2048
  float* cosT  = (float*)(w + 67108864);  //    524,288
  float* sinT  = (float*)(w + 67633152);  //    524,288
  u16* wo16 = wqkv16;                     // alias (wqkv16 dead after QKV gemm)
  u16* attnout = x16;                     // alias (x16 dead after QKV gemm)

  rope_tables<<<512, 256, 0, stream>>>(cosT, sinT);
  cvt_bf16<<<4096, 256, 0, stream>>>(x,  x16);
  cvt_bf16<<<2048, 256, 0, stream>>>(wq, wqkv16);                  // rows 0-2047
  cvt_bf16<<<1024, 256, 0, stream>>>(wk, wqkv16 + 2048 * 2048);    // rows 2048-3071
  cvt_bf16<<<1024, 256, 0, stream>>>(wv, wqkv16 + 3072 * 2048);    // rows 3072-4095
  gemm_qkv<<<1024, 256, 0, stream>>>(x16, wqkv16, Qh, Kh, Vt);
  cvt_bf16<<<2048, 256, 0, stream>>>(wo, wo16);   // into wqkv16 space (dead)
  rope_inplace<<<4096, 256, 0, stream>>>(Qh, cosT, sinT, 0.08838834764831845f);
  rope_inplace<<<2048, 256, 0, stream>>>(Kh, cosT, sinT, 1.0f);
  attn_fwd<<<1024, 256, 0, stream>>>(Qh, Kh, Vt, attnout);
  gemm_out<<<dim3(16, 32), 256, 0, stream>>>(attnout, wo16, out, 4096, 2048, 2048);
}

// Round 9
// 454.569 us; speedup vs baseline: 1.7393x; 1.0016x over previous
//
#include <hip/hip_runtime.h>

// Problem constants
#define S_LEN 2048
#define DM    2048
#define HQ_N  16
#define HKV_N 8
#define HD    128

typedef unsigned short u16;
typedef unsigned int   u32;
typedef short bf16x8 __attribute__((ext_vector_type(8)));
typedef float f32x4  __attribute__((ext_vector_type(4)));
typedef u16   u16x8  __attribute__((ext_vector_type(8)));

__device__ __forceinline__ float b2f(u16 u) {
  u32 x = ((u32)u) << 16;
  return __builtin_bit_cast(float, x);
}
__device__ __forceinline__ u16 f2b(float f) {  // RNE
  u32 u = __builtin_bit_cast(u32, f);
  u32 r = u + 0x7fffu + ((u >> 16) & 1u);
  return (u16)(r >> 16);
}

// direct global->LDS DMA, 16B per lane (dest = wave-uniform base + lane*16)
#define GLOAD_LDS16(g, l)                                                     \
  __builtin_amdgcn_global_load_lds(                                           \
      (const __attribute__((address_space(1))) void*)(g),                     \
      (__attribute__((address_space(3))) void*)(l), 16, 0, 0)

// ---------------- f32 -> bf16 bulk convert (8 elems/thread) ---------------
__global__ void cvt_bf16(const float* __restrict__ src, u16* __restrict__ dst) {
  int id = blockIdx.x * blockDim.x + threadIdx.x;
  float4 a = ((const float4*)src)[id * 2];
  float4 b = ((const float4*)src)[id * 2 + 1];
  u16x8 o;
  o[0] = f2b(a.x); o[1] = f2b(a.y); o[2] = f2b(a.z); o[3] = f2b(a.w);
  o[4] = f2b(b.x); o[5] = f2b(b.y); o[6] = f2b(b.z); o[7] = f2b(b.w);
  ((u16x8*)dst)[id] = o;
}

// ---------------- RoPE tables: cos/sin[t][i], t<2048, i<64 ----------------
__global__ void rope_tables(float* __restrict__ cosT, float* __restrict__ sinT) {
  int id = blockIdx.x * blockDim.x + threadIdx.x;  // 131072
  int t = id >> 6, i = id & 63;
  float inv = (float)pow(10000.0, -(double)(2 * i) / 128.0);
  float ang = (float)t * inv;
  cosT[id] = cosf(ang);
  sinT[id] = sinf(ang);
}

// ---------------- Fused QKV GEMM + RoPE epilogue --------------------------
// C(4096x4096) = x16 * wqkv^T; wq rows 0-2047, wk 2048-3071, wv 3072-4095.
// Epilogue: RoPE on Q/K regions (pairing adjacent cols via shfl_xor lane^1),
// Q scaled by 1/sqrt(128); routes:
//   cols 0-2047  -> Qh[((b*16+h)*S+s)*128+d]
//   cols 2048-.. -> Kh[((b*8+hk)*S+s)*128+d]
//   cols 3072-.. -> Vt[((b*8+hk)*128+d)*S+s]   (V transposed for PV)
__global__ __launch_bounds__(256) void gemm_qkv(const u16* __restrict__ A,
                                                const u16* __restrict__ W,
                                                const float* __restrict__ cosT,
                                                const float* __restrict__ sinT,
                                                u16* __restrict__ Qh,
                                                u16* __restrict__ Kh,
                                                u16* __restrict__ Vt) {
  __shared__ alignas(16) u16 As[128 * 32];
  __shared__ alignas(16) u16 Bs[128 * 32];
  const int K = DM;
  const int tid  = threadIdx.x;
  const int lane = tid & 63;
  const int wave = tid >> 6;
  const int wr = (wave >> 1) * 64;
  const int wc = (wave & 1) * 64;
  const int orig = (blockIdx.x & 7) * 128 + (blockIdx.x >> 3);  // XCD-grouped
  const int bn = (orig >> 5) * 128;
  const int bm = (orig & 31) * 128;
  const int r0 = tid >> 2;
  const int c0 = (tid & 3) * 8;
  u16* AsD = &As[tid * 8];
  u16* BsD = &Bs[tid * 8];
  const u16* Ap = A + (size_t)(bm + r0) * K + c0;
  const u16* Wp = W + (size_t)(bn + r0) * K + c0;
  const int cl = lane & 15;
  const int g8 = (lane >> 4) * 8;
  f32x4 acc[4][4] = {};
  for (int k0 = 0; k0 < K; k0 += 32) {
    __syncthreads();
    GLOAD_LDS16(Ap + k0, AsD);
    GLOAD_LDS16(Ap + (size_t)64 * K + k0, AsD + 2048);
    GLOAD_LDS16(Wp + k0, BsD);
    GLOAD_LDS16(Wp + (size_t)64 * K + k0, BsD + 2048);
    __syncthreads();
    bf16x8 af[4], bfr[4];
#pragma unroll
    for (int m = 0; m < 4; ++m)
      af[m] = *(const bf16x8*)&As[(wr + m * 16 + cl) * 32 + g8];
#pragma unroll
    for (int n = 0; n < 4; ++n)
      bfr[n] = *(const bf16x8*)&Bs[(wc + n * 16 + cl) * 32 + g8];
#pragma unroll
    for (int m = 0; m < 4; ++m)
#pragma unroll
      for (int n = 0; n < 4; ++n)
        acc[m][n] = __builtin_amdgcn_mfma_f32_16x16x32_bf16(af[m], bfr[n], acc[m][n], 0, 0, 0);
  }
  const int g4 = (lane >> 4) * 4;
#pragma unroll
  for (int m = 0; m < 4; ++m)
#pragma unroll
    for (int n = 0; n < 4; ++n)
#pragma unroll
      for (int r = 0; r < 4; ++r) {
        int row = bm + wr + m * 16 + g4 + r;   // b*S + s
        int col = bn + wc + n * 16 + cl;       // 0..4095
        int bb = row >> 11, s = row & (S_LEN - 1);
        float fv = acc[m][n][r];
        float ov = fv;
        if (bn < 3072) {  // Q or K region: apply RoPE (block-uniform branch)
          int d = col & (HD - 1);
          int i = d >> 1;
          float c  = cosT[s * 64 + i];
          float sn = sinT[s * 64 + i];
          float par = __shfl_xor(fv, 1);  // partner col (d^1), same row
          ov = (d & 1) ? (par * sn + fv * c) : (fv * c - par * sn);
          if (bn < 2048) ov *= 0.08838834764831845f;  // 1/sqrt(128) on Q
        }
        u16 v = f2b(ov);
        if (bn < 2048) {        // Q
          int h = col >> 7, d = col & (HD - 1);
          Qh[((size_t)((bb * HQ_N + h) * S_LEN + s)) * HD + d] = v;
        } else if (bn < 3072) { // K
          int hk = (col >> 7) - 16, d = col & (HD - 1);
          Kh[((size_t)((bb * HKV_N + hk) * S_LEN + s)) * HD + d] = v;
        } else {                // V -> transposed
          int hk = (col >> 7) - 24, d = col & (HD - 1);
          Vt[((size_t)((bb * HKV_N + hk) * HD + d)) * S_LEN + s] = v;
        }
      }
}

// ---------------- Output GEMM: out(4096x2048 f32) = attnout * wo^T --------
__global__ __launch_bounds__(256) void gemm_out(const u16* __restrict__ A,
                                                const u16* __restrict__ W,
                                                float* __restrict__ C,
                                                int M, int N, int K) {
  __shared__ alignas(16) u16 As[128 * 32];
  __shared__ alignas(16) u16 Bs[128 * 32];
  const int tid  = threadIdx.x;
  const int lane = tid & 63;
  const int wave = tid >> 6;
  const int wr = (wave >> 1) * 64;
  const int wc = (wave & 1) * 64;
  const int bm = blockIdx.y * 128;
  const int bn = blockIdx.x * 128;
  const int r0 = tid >> 2;
  const int c0 = (tid & 3) * 8;
  u16* AsD = &As[tid * 8];
  u16* BsD = &Bs[tid * 8];
  const u16* Ap = A + (size_t)(bm + r0) * K + c0;
  const u16* Wp = W + (size_t)(bn + r0) * K + c0;
  const int cl = lane & 15;
  const int g8 = (lane >> 4) * 8;
  f32x4 acc[4][4] = {};
  for (int k0 = 0; k0 < K; k0 += 32) {
    __syncthreads();
    GLOAD_LDS16(Ap + k0, AsD);
    GLOAD_LDS16(Ap + (size_t)64 * K + k0, AsD + 2048);
    GLOAD_LDS16(Wp + k0, BsD);
    GLOAD_LDS16(Wp + (size_t)64 * K + k0, BsD + 2048);
    __syncthreads();
    bf16x8 af[4], bfr[4];
#pragma unroll
    for (int m = 0; m < 4; ++m)
      af[m] = *(const bf16x8*)&As[(wr + m * 16 + cl) * 32 + g8];
#pragma unroll
    for (int n = 0; n < 4; ++n)
      bfr[n] = *(const bf16x8*)&Bs[(wc + n * 16 + cl) * 32 + g8];
#pragma unroll
    for (int m = 0; m < 4; ++m)
#pragma unroll
      for (int n = 0; n < 4; ++n)
        acc[m][n] = __builtin_amdgcn_mfma_f32_16x16x32_bf16(af[m], bfr[n], acc[m][n], 0, 0, 0);
  }
  const int g4 = (lane >> 4) * 4;
#pragma unroll
  for (int m = 0; m < 4; ++m)
#pragma unroll
    for (int n = 0; n < 4; ++n)
#pragma unroll
      for (int r = 0; r < 4; ++r) {
        int row = bm + wr + m * 16 + g4 + r;
        int col = bn + wc + n * 16 + cl;
        C[(size_t)row * N + col] = acc[m][n][r];
      }
}

// ---------------- Flash attention: overlapped 2-phase staging -------------
// Per tile: phase A = {issue V(t) stage || QK^T+softmax from Ks} barrier;
//           phase B = {issue K(t+1) stage || PV from Vs} barrier.
// __syncthreads drains vmcnt -> staged data ready; stages always overlap a
// full compute phase (T3-minimum). Single K buf + single V buf (40KB LDS).
__global__ __launch_bounds__(256, 4) void attn_fwd(const u16* __restrict__ Q,
                                                   const u16* __restrict__ Kh,
                                                   const u16* __restrict__ Vt,
                                                   u16* __restrict__ O) {
  __shared__ alignas(16) u16 Ks[64 * 128];      // [key][d], cols XOR-swizzled
  __shared__ alignas(16) u16 Vs[128 * 64];      // [d][key], cols XOR-swizzled
  __shared__ alignas(16) u16 Plds[4][2][16 * 32];
  const int tid  = threadIdx.x;
  const int wave = tid >> 6;
  const int lane = tid & 63;
  const int orig = (blockIdx.x & 7) * 128 + (blockIdx.x >> 3);  // XCD-grouped
  const int bh = orig >> 5;                 // b*HQ + h
  const int j = orig & 31;
  const int qblk = (j & 1) ? ((j - 1) >> 1) : (31 - (j >> 1));
  const int bb = bh >> 4, h = bh & 15;
  const int bkv = bb * HKV_N + (h >> 1);
  const u16* Kp = Kh + (size_t)bkv * S_LEN * HD;
  const u16* Vp = Vt + (size_t)bkv * HD * S_LEN;
  const int cl = lane & 15;
  const int gr = lane >> 4;
  const int g8 = gr * 8;
  const int sw8 = (cl & 7) << 3;
  const int q0w = qblk * 64 + wave * 16;
  const u16* Qp = Q + ((size_t)bh * S_LEN + q0w) * HD;
  bf16x8 qf[4];
#pragma unroll
  for (int c = 0; c < 4; ++c)
    qf[c] = *(const bf16x8*)&Qp[cl * HD + c * 32 + g8];
  // staging source addrs (pre-swizzled so linear LDS dest == swizzled layout)
  const int krow_w = wave * 4 + gr;
  const int kcol = (cl * 8) ^ ((krow_w & 7) << 3);
  const u16* kSrc = Kp + (size_t)krow_w * HD + kcol;
  const int vrow_w = wave * 8 + (lane >> 3);
  const int vcol = ((lane & 7) * 8) ^ (((lane >> 3) & 7) << 3);
  const u16* vSrc = Vp + (size_t)vrow_w * S_LEN + vcol;
  float m[4]    = {-1e30f, -1e30f, -1e30f, -1e30f};
  float lsum[4] = {0.f, 0.f, 0.f, 0.f};
  f32x4 oacc[8] = {};
  u16* Pw0 = &Plds[wave][0][0];
  u16* Pw1 = &Plds[wave][1][0];
  // prologue: stage K tile 0
#pragma unroll
  for (int j2 = 0; j2 < 4; ++j2)
    GLOAD_LDS16(kSrc + (size_t)(j2 * 16) * HD, &Ks[(j2 * 4 + wave) * 512]);
  __syncthreads();
  for (int t = 0; t <= qblk; ++t) {
    const int k0 = t * 64;
    // ---- phase A: issue V(t) stage, then QK^T + softmax from Ks ----
#pragma unroll
    for (int j2 = 0; j2 < 4; ++j2)
      GLOAD_LDS16(vSrc + (size_t)j2 * 32 * S_LEN + k0, &Vs[(j2 * 4 + wave) * 512]);
    f32x4 sc[4] = {{0.f, 0.f, 0.f, 0.f}, {0.f, 0.f, 0.f, 0.f},
                   {0.f, 0.f, 0.f, 0.f}, {0.f, 0.f, 0.f, 0.f}};
#pragma unroll
    for (int c = 0; c < 4; ++c) {
      const int kq = (c * 32 + g8) ^ sw8;
#pragma unroll
      for (int ks = 0; ks < 4; ++ks) {
        bf16x8 kf = *(const bf16x8*)&Ks[(ks * 16 + cl) * 128 + kq];
        sc[ks] = __builtin_amdgcn_mfma_f32_16x16x32_bf16(qf[c], kf, sc[ks], 0, 0, 0);
      }
    }
    float corr[4];
    if (t == qblk) {
#pragma unroll
      for (int r = 0; r < 4; ++r) {
        const int qrel = wave * 16 + gr * 4 + r;
#pragma unroll
        for (int ks = 0; ks < 4; ++ks)
          if (ks * 16 + cl > qrel) sc[ks][r] = -1e30f;
      }
    }
#pragma unroll
    for (int r = 0; r < 4; ++r) {
      float mx = fmaxf(fmaxf(sc[0][r], sc[1][r]), fmaxf(sc[2][r], sc[3][r]));
#pragma unroll
      for (int off = 1; off < 16; off <<= 1)
        mx = fmaxf(mx, __shfl_xor(mx, off));
      const float mn = fmaxf(m[r], mx);
      corr[r] = __expf(m[r] - mn);
      float p0 = __expf(sc[0][r] - mn);
      float p1 = __expf(sc[1][r] - mn);
      float p2 = __expf(sc[2][r] - mn);
      float p3 = __expf(sc[3][r] - mn);
      float rs = (p0 + p1) + (p2 + p3);
#pragma unroll
      for (int off = 1; off < 16; off <<= 1)
        rs += __shfl_xor(rs, off);
      lsum[r] = lsum[r] * corr[r] + rs;
      m[r] = mn;
      const int row = gr * 4 + r;
      Pw0[row * 32 + cl]      = f2b(p0);
      Pw0[row * 32 + 16 + cl] = f2b(p1);
      Pw1[row * 32 + cl]      = f2b(p2);
      Pw1[row * 32 + 16 + cl] = f2b(p3);
    }
#pragma unroll
    for (int nd = 0; nd < 8; ++nd)
#pragma unroll
      for (int r = 0; r < 4; ++r) oacc[nd][r] *= corr[r];
    __syncthreads();  // drains V(t) stage + P writes; Ks readers done
    // ---- phase B: issue K(t+1) stage, then PV from Vs ----
    if (t < qblk) {
#pragma unroll
      for (int j2 = 0; j2 < 4; ++j2)
        GLOAD_LDS16(kSrc + (size_t)(k0 + 64 + j2 * 16) * HD,
                    &Ks[(j2 * 4 + wave) * 512]);
    }
    bf16x8 pa0 = *(const bf16x8*)&Pw0[cl * 32 + g8];
    bf16x8 pa1 = *(const bf16x8*)&Pw1[cl * 32 + g8];
    const int vq0 = g8 ^ sw8;
    const int vq1 = (32 + g8) ^ sw8;
#pragma unroll
    for (int nd = 0; nd < 8; ++nd) {
      bf16x8 vf0 = *(const bf16x8*)&Vs[(nd * 16 + cl) * 64 + vq0];
      bf16x8 vf1 = *(const bf16x8*)&Vs[(nd * 16 + cl) * 64 + vq1];
      oacc[nd] = __builtin_amdgcn_mfma_f32_16x16x32_bf16(pa0, vf0, oacc[nd], 0, 0, 0);
      oacc[nd] = __builtin_amdgcn_mfma_f32_16x16x32_bf16(pa1, vf1, oacc[nd], 0, 0, 0);
    }
    __syncthreads();  // drains K(t+1) stage; Vs readers done
  }
#pragma unroll
  for (int r = 0; r < 4; ++r) {
    const int q = q0w + gr * 4 + r;
    const float inv = 1.0f / lsum[r];
#pragma unroll
    for (int nd = 0; nd < 8; ++nd)
      O[(((size_t)bb * S_LEN + q) * HQ_N + h) * HD + nd * 16 + cl] =
          f2b(oacc[nd][r] * inv);
  }
}

// ---------------- launch ---------------------------------------------------
extern "C" void kernel_launch(void* const* d_in, const int* in_sizes, int n_in,
                              void* d_out, int out_size, void* d_ws, size_t ws_size,
                              hipStream_t stream) {
  (void)in_sizes; (void)n_in; (void)out_size; (void)ws_size;
  const float* x  = (const float*)d_in[0];
  const float* wq = (const float*)d_in[1];
  const float* wk = (const float*)d_in[2];
  const float* wv = (const float*)d_in[3];
  const float* wo = (const float*)d_in[4];
  float* out = (float*)d_out;
  char* w = (char*)d_ws;
  // workspace map (bytes), total ~68.2 MB
  u16*  Qh     = (u16*)(w + 0);           // 16,777,216  [(b*16+h)*S+s][d]
  u16*  Kh     = (u16*)(w + 16777216);    //  8,388,608  [(b*8+hk)*S+s][d]
  u16*  Vt     = (u16*)(w + 25165824);    //  8,388,608  [(b*8+hk)*128+d][s]
  u16*  x16    = (u16*)(w + 33554432);    // 16,777,216  (attnout alias after QKV)
  u16*  wqkv16 = (u16*)(w + 50331648);    // 16,777,216  [wq;wk;wv] rows x 2048
  float* cosT  = (float*)(w + 67108864);  //    524,288
  float* sinT  = (float*)(w + 67633152);  //    524,288
  u16* wo16 = wqkv16;                     // alias (wqkv16 dead after QKV gemm)
  u16* attnout = x16;                     // alias (x16 dead after QKV gemm)

  rope_tables<<<512, 256, 0, stream>>>(cosT, sinT);
  cvt_bf16<<<4096, 256, 0, stream>>>(x,  x16);
  cvt_bf16<<<2048, 256, 0, stream>>>(wq, wqkv16);                  // rows 0-2047
  cvt_bf16<<<1024, 256, 0, stream>>>(wk, wqkv16 + 2048 * 2048);    // rows 2048-3071
  cvt_bf16<<<1024, 256, 0, stream>>>(wv, wqkv16 + 3072 * 2048);    // rows 3072-4095
  gemm_qkv<<<1024, 256, 0, stream>>>(x16, wqkv16, cosT, sinT, Qh, Kh, Vt);
  cvt_bf16<<<2048, 256, 0, stream>>>(wo, wo16);   // into wqkv16 space (dead)
  attn_fwd<<<1024, 256, 0, stream>>>(Qh, Kh, Vt, attnout);
  gemm_out<<<dim3(16, 32), 256, 0, stream>>>(attnout, wo16, out, 4096, 2048, 2048);
}